// Round 5
// baseline (310.330 us; speedup 1.0000x reference)
//
#include <hip/hip_runtime.h>
#include <hip/hip_fp16.h>

// Problem constants: L=4, DIM=17, S=4, B=4, H=256, W=256, BINSIZE=16
#define HH   256
#define WW   256
#define HWPX (HH * WW)           // 65536
#define DD   17
#define D4   (17 * 17 * 17 * 17) // 83521
#define NL   4
#define SS   16                  // S*S
#define NPIX (4 * HWPX)          // 262144 pixels
#define LUT_FLOATS  (NL * D4 * SS)            // 5,345,344 floats
#define LUT_BYTES_H ((size_t)LUT_FLOATS * 2)  // ~10.7 MB (fp16 transposed copy)

// Binning: bin = flat0 >> 9. flat0 max = 15*5220 = 78300 -> 153 bins. Pad 160.
#define NBINS     160
#define BIN_SHIFT 9

// Workspace byte offsets
#define WSO_HIST    0u              // 160 u32 (zeroed each iter)
#define WSO_CURSOR  1024u           // 160 u32
#define WSO_SORTP   (1u << 20)      // 262144 u32  (1 MB)
#define WSO_WA      (4u << 20)      // 262144 float2 (2 MB) : wl0, wl1
#define WSO_WB      (8u << 20)      // 262144 float2 (2 MB) : wl2, wl3
#define WSO_LUT     (12u << 20)     // fp16 transposed LUT (~10.7 MB)
#define WS_NEED     ((size_t)WSO_LUT + LUT_BYTES_H)

// ---------------------------------------------------------------------------
// Shared per-pixel index math (identical FP ops in every pass -> identical
// flat0 / fracs everywhere).
// ---------------------------------------------------------------------------
__device__ __forceinline__ void pixel_base(
    const float* __restrict__ x, int p,
    int& b, int& hw,
    int& bq0, int& bq1, int& bq2, int& bq3,
    float& f0, float& f1, float& f2, float& f3)
{
    b  = p >> 16;
    hw = p & 65535;
    int h = hw >> 8, w = hw & 255;
    const float* xb = x + b * HWPX;
    int h1 = (h + 1 < HH) ? (h + 1) : (HH - 2);   // reflect pad
    int w1 = (w + 1 < WW) ? (w + 1) : (WW - 2);

    float pix0 = xb[h  * WW + w ];
    float pix1 = xb[h  * WW + w1];
    float pix2 = xb[h1 * WW + w ];
    float pix3 = xb[h1 * WW + w1];

    const float inv = 1.0f / 16.0f;
    float t0 = pix0 * inv, t1 = pix1 * inv, t2 = pix2 * inv, t3 = pix3 * inv;
    float bf0 = floorf(t0), bf1 = floorf(t1), bf2 = floorf(t2), bf3 = floorf(t3);
    f0 = t0 - bf0; f1 = t1 - bf1; f2 = t2 - bf2; f3 = t3 - bf3;

    bq0 = min(max((int)bf0, 0), DD - 2);
    bq1 = min(max((int)bf1, 0), DD - 2);
    bq2 = min(max((int)bf2, 0), DD - 2);
    bq3 = min(max((int)bf3, 0), DD - 2);
}

// ---------------------------------------------------------------------------
// Kernel 1: transpose + fp16-convert LUT (L, D4, 16) f32 -> (D4, L, 16) f16.
// One vertex's four l-rows become exactly ONE 128B cache line.
// ---------------------------------------------------------------------------
__global__ __launch_bounds__(256) void lut_transpose_h_kernel(
    const float4* __restrict__ src,   // (L, D4, 4) float4
    ushort* __restrict__ dst)         // (D4, L, 16) halfs as ushort
{
    int t = blockIdx.x * blockDim.x + threadIdx.x;  // 4-half chunk index in dst
    if (t >= D4 * NL * 4) return;
    int c4 = t & 3;
    int l  = (t >> 2) & 3;
    int v  = t >> 4;
    float4 r = src[(size_t)l * (D4 * 4) + (size_t)v * 4 + c4];
    ushort4 h;
    h.x = __half_as_ushort(__float2half_rn(r.x));
    h.y = __half_as_ushort(__float2half_rn(r.y));
    h.z = __half_as_ushort(__float2half_rn(r.z));
    h.w = __half_as_ushort(__float2half_rn(r.w));
    *((ushort4*)(dst + (size_t)t * 4)) = h;   // coalesced 8B stores
}

// ---------------------------------------------------------------------------
// P0: zero hist + cursor (workspace is poisoned each iteration).
// ---------------------------------------------------------------------------
__global__ __launch_bounds__(256) void lut4d_zero_meta(unsigned* __restrict__ ws)
{
    int t = threadIdx.x;
    ws[t]       = 0;   // hist region  (u32 idx 0..255, used 0..159)
    ws[256 + t] = 0;   // cursor region (u32 idx 256..511, used 256..415)
}

// ---------------------------------------------------------------------------
// P1: histogram of bin(flat0) over all pixels. LDS-aggregated.
// ---------------------------------------------------------------------------
__global__ __launch_bounds__(256) void lut4d_hist(
    const float* __restrict__ x, unsigned* __restrict__ hist)
{
    __shared__ unsigned lh[NBINS];
    int t = threadIdx.x;
    if (t < NBINS) lh[t] = 0;
    __syncthreads();

    int p = blockIdx.x * 256 + t;
    int b, hw, b0, b1, b2, b3; float f0, f1, f2, f3;
    pixel_base(x, p, b, hw, b0, b1, b2, b3, f0, f1, f2, f3);
    int flat0 = ((b0 * DD + b1) * DD + b2) * DD + b3;
    atomicAdd(&lh[flat0 >> BIN_SHIFT], 1u);
    __syncthreads();

    if (t < NBINS) {
        unsigned c = lh[t];
        if (c) atomicAdd(&hist[t], c);
    }
}

// ---------------------------------------------------------------------------
// P2: exclusive scan of hist -> cursor. One block, 256 threads.
// ---------------------------------------------------------------------------
__global__ __launch_bounds__(256) void lut4d_scan(
    const unsigned* __restrict__ hist, unsigned* __restrict__ cursor)
{
    __shared__ unsigned sdat[256];
    int t = threadIdx.x;
    unsigned v = (t < NBINS) ? hist[t] : 0u;
    sdat[t] = v;
    __syncthreads();
#pragma unroll
    for (int off = 1; off < 256; off <<= 1) {
        unsigned a = (t >= off) ? sdat[t - off] : 0u;
        __syncthreads();
        sdat[t] += a;
        __syncthreads();
    }
    if (t < NBINS) cursor[t] = sdat[t] - v;   // exclusive prefix
}

// ---------------------------------------------------------------------------
// P3: scatter pixel ids (+ their 4 lut-weights, read COALESCED here) into
// flat0-bin-sorted order. Within-bin order is nondeterministic (atomic) but
// each pixel appears exactly once -> output invariant.
// ---------------------------------------------------------------------------
__global__ __launch_bounds__(256) void lut4d_scatter(
    const float* __restrict__ x, const float* __restrict__ weight,
    unsigned* __restrict__ cursor,
    unsigned* __restrict__ sortP, float2* __restrict__ wA, float2* __restrict__ wB)
{
    int p = blockIdx.x * 256 + threadIdx.x;
    int b, hw, b0, b1, b2, b3; float f0, f1, f2, f3;
    pixel_base(x, p, b, hw, b0, b1, b2, b3, f0, f1, f2, f3);
    int flat0 = ((b0 * DD + b1) * DD + b2) * DD + b3;
    int bin = flat0 >> BIN_SHIFT;

    const float* wb = weight + b * (NL * HWPX) + hw;   // coalesced (p-order)
    float wl0 = wb[0 * HWPX], wl1 = wb[1 * HWPX];
    float wl2 = wb[2 * HWPX], wl3 = wb[3 * HWPX];

    unsigned pos = atomicAdd(&cursor[bin], 1u);
    sortP[pos] = (unsigned)p;
    wA[pos] = make_float2(wl0, wl1);
    wB[pos] = make_float2(wl2, wl3);
}

// ---------------------------------------------------------------------------
// P4: main interpolation over SORTED pixel order with XCD-affinity swizzle.
// 8 lanes per pixel; lane j does ONE dwordx4 (16B) load per vertex; the 8
// lanes tile the 128B vertex line. Sorted sweep => each XCD's LUT window
// (~1.5 MB) stays L2-resident; LUT L3 traffic drops ~10x.
// ---------------------------------------------------------------------------
__global__ __launch_bounds__(256) void lut4d_main_sorted(
    const ushort* __restrict__ lutT,   // (D4, L, 16) fp16
    const unsigned* __restrict__ sortP,
    const float2* __restrict__ wA, const float2* __restrict__ wB,
    const float* __restrict__ x,       // (B, 1, H, W)
    float* __restrict__ out)           // (B, 1, H*4, W*4)
{
    // XCD-affinity: launch-idx % 8 == XCD (heuristic); give XCD k the
    // contiguous sorted chunk [k*1024, (k+1)*1024) of record-blocks.
    int c = (blockIdx.x & 7) * 1024 + (blockIdx.x >> 3);     // logical chunk
    int t = threadIdx.x;
    int j = t & 7;                 // sub-pixel lane: l = j>>1, half = j&1
    int sidx = c * 32 + (t >> 3);  // sorted record index
    int l = j >> 1;

    int p = (int)sortP[sidx];
    float2 fa = wA[sidx];
    float2 fb = wB[sidx];
    float wlv = (l == 0) ? fa.x : (l == 1) ? fa.y : (l == 2) ? fb.x : fb.y;

    int b, hw, b0, b1, b2, b3; float f0, f1, f2, f3;
    pixel_base(x, p, b, hw, b0, b1, b2, b3, f0, f1, f2, f3);
    int h = hw >> 8, w = hw & 255;

    // Stable descending sort of (frac, stride); strides strictly decrease
    // with original index so tie-break by larger stride == stable argsort.
    float s0f = f0, s1f = f1, s2f = f2, s3f = f3;
    int   s0s = 4913, s1s = 289, s2s = 17, s3s = 1;

#define CSWAP(fa_, sa_, fb_, sb_)                                      \
    do {                                                               \
        bool sw = (fb_ > fa_) || ((fb_ == fa_) && (sb_ > sa_));        \
        float tf = fa_; int ts = sa_;                                  \
        if (sw) { fa_ = fb_; sa_ = sb_; fb_ = tf; sb_ = ts; }          \
    } while (0)

    CSWAP(s0f, s0s, s1f, s1s);
    CSWAP(s2f, s2s, s3f, s3s);
    CSWAP(s0f, s0s, s2f, s2s);
    CSWAP(s1f, s1s, s3f, s3s);
    CSWAP(s1f, s1s, s2f, s2s);
#undef CSWAP

    float wts[5];
    wts[0] = 1.0f - s0f;
    wts[1] = s0f - s1f;
    wts[2] = s1f - s2f;
    wts[3] = s2f - s3f;
    wts[4] = s3f;

    int flats[5];
    flats[0] = ((b0 * DD + b1) * DD + b2) * DD + b3;
    flats[1] = flats[0] + s0s;
    flats[2] = flats[1] + s1s;
    flats[3] = flats[2] + s2s;
    flats[4] = flats[3] + s3s;

    // 5 independent 16B gathers: lane j covers bytes [j*16, j*16+16) of the
    // 128B vertex line (L2-resident by sorted sweep).
    uint4 r[5];
#pragma unroll
    for (int k = 0; k < 5; ++k) {
        const ushort* vbase = lutT + (size_t)flats[k] * (NL * SS);
        r[k] = *((const uint4*)(vbase) + j);
    }

    float acc0 = 0.f, acc1 = 0.f, acc2 = 0.f, acc3 = 0.f;
    float acc4 = 0.f, acc5 = 0.f, acc6 = 0.f, acc7 = 0.f;
#pragma unroll
    for (int k = 0; k < 5; ++k) {
        float cw = wlv * wts[k];
        float2 f0v = __half22float2(*reinterpret_cast<const __half2*>(&r[k].x));
        float2 f1v = __half22float2(*reinterpret_cast<const __half2*>(&r[k].y));
        float2 f2v = __half22float2(*reinterpret_cast<const __half2*>(&r[k].z));
        float2 f3v = __half22float2(*reinterpret_cast<const __half2*>(&r[k].w));
        acc0 = fmaf(cw, f0v.x, acc0);
        acc1 = fmaf(cw, f0v.y, acc1);
        acc2 = fmaf(cw, f1v.x, acc2);
        acc3 = fmaf(cw, f1v.y, acc3);
        acc4 = fmaf(cw, f2v.x, acc4);
        acc5 = fmaf(cw, f2v.y, acc5);
        acc6 = fmaf(cw, f3v.x, acc6);
        acc7 = fmaf(cw, f3v.y, acc7);
    }

    // Butterfly-sum across the 4 l-lanes (same j&1): masks 2 then 4.
#define RED(mask)                                                      \
    do {                                                               \
        acc0 += __shfl_xor(acc0, mask, 64);                            \
        acc1 += __shfl_xor(acc1, mask, 64);                            \
        acc2 += __shfl_xor(acc2, mask, 64);                            \
        acc3 += __shfl_xor(acc3, mask, 64);                            \
        acc4 += __shfl_xor(acc4, mask, 64);                            \
        acc5 += __shfl_xor(acc5, mask, 64);                            \
        acc6 += __shfl_xor(acc6, mask, 64);                            \
        acc7 += __shfl_xor(acc7, mask, 64);                            \
    } while (0)
    RED(2);
    RED(4);
#undef RED

    // Lane j writes global channels c0 = (j&1)*8 + (j>>1)*2, c0+1.
    int sel = j >> 1;
    float o0 = (sel == 0) ? acc0 : (sel == 1) ? acc2 : (sel == 2) ? acc4 : acc6;
    float o1 = (sel == 0) ? acc1 : (sel == 1) ? acc3 : (sel == 2) ? acc5 : acc7;

    int c0  = (j & 1) * 8 + sel * 2;
    int row = c0 >> 2;        // s-row
    int col = c0 & 3;         // s-col
    float* ob = out + (size_t)b * (HH * 4) * (WW * 4)
                    + (size_t)(h * 4 + row) * (WW * 4)
                    + (w * 4) + col;
    *((float2*)ob) = make_float2(o0, o1);
}

// ---------------------------------------------------------------------------
// Fallback (no workspace): original layout, fp32.
// ---------------------------------------------------------------------------
__global__ __launch_bounds__(256) void lut4d_kernel_fallback(
    const float* __restrict__ lut,
    const float* __restrict__ weight,
    const float* __restrict__ x,
    float* __restrict__ out)
{
    int p = blockIdx.x * blockDim.x + threadIdx.x;
    int b, hw, b0, b1, b2, b3; float f0, f1, f2, f3;
    pixel_base(x, p, b, hw, b0, b1, b2, b3, f0, f1, f2, f3);
    int h = hw >> 8, w = hw & 255;

    float s0f = f0, s1f = f1, s2f = f2, s3f = f3;
    int   s0s = 4913, s1s = 289, s2s = 17, s3s = 1;

#define CSWAP(fa_, sa_, fb_, sb_)                                      \
    do {                                                               \
        bool sw = (fb_ > fa_) || ((fb_ == fa_) && (sb_ > sa_));        \
        float tf = fa_; int ts = sa_;                                  \
        if (sw) { fa_ = fb_; sa_ = sb_; fb_ = tf; sb_ = ts; }          \
    } while (0)

    CSWAP(s0f, s0s, s1f, s1s);
    CSWAP(s2f, s2s, s3f, s3s);
    CSWAP(s0f, s0s, s2f, s2s);
    CSWAP(s1f, s1s, s3f, s3s);
    CSWAP(s1f, s1s, s2f, s2s);
#undef CSWAP

    float wts[5] = { 1.0f - s0f, s0f - s1f, s1f - s2f, s2f - s3f, s3f };
    int flats[5];
    flats[0] = ((b0 * DD + b1) * DD + b2) * DD + b3;
    flats[1] = flats[0] + s0s;
    flats[2] = flats[1] + s1s;
    flats[3] = flats[2] + s2s;
    flats[4] = flats[3] + s3s;

    float acc[SS];
#pragma unroll
    for (int i = 0; i < SS; ++i) acc[i] = 0.0f;

    const float* wb = weight + b * (NL * HWPX) + hw;

#pragma unroll
    for (int l = 0; l < NL; ++l) {
        float wlv = wb[l * HWPX];
        const float* lbase = lut + (size_t)l * D4 * SS;
#pragma unroll
        for (int k = 0; k < 5; ++k) {
            float cw = wlv * wts[k];
            const float4* row = (const float4*)(lbase + (size_t)flats[k] * SS);
#pragma unroll
            for (int q = 0; q < 4; ++q) {
                float4 rr = row[q];
                acc[q * 4 + 0] = fmaf(cw, rr.x, acc[q * 4 + 0]);
                acc[q * 4 + 1] = fmaf(cw, rr.y, acc[q * 4 + 1]);
                acc[q * 4 + 2] = fmaf(cw, rr.z, acc[q * 4 + 2]);
                acc[q * 4 + 3] = fmaf(cw, rr.w, acc[q * 4 + 3]);
            }
        }
    }

    float* ob = out + (size_t)b * (HH * 4) * (WW * 4) + (size_t)(h * 4) * (WW * 4) + (w * 4);
#pragma unroll
    for (int i = 0; i < 4; ++i) {
        *((float4*)(ob + (size_t)i * (WW * 4))) =
            make_float4(acc[i * 4 + 0], acc[i * 4 + 1], acc[i * 4 + 2], acc[i * 4 + 3]);
    }
}

extern "C" void kernel_launch(void* const* d_in, const int* in_sizes, int n_in,
                              void* d_out, int out_size, void* d_ws, size_t ws_size,
                              hipStream_t stream) {
    const float* lut    = (const float*)d_in[0];
    // d_in[1] = tri_index (unused by the reference computation)
    const float* weight = (const float*)d_in[2];
    const float* x      = (const float*)d_in[3];
    float* out          = (float*)d_out;

    dim3 block(256);

    if (ws_size >= WS_NEED) {
        char* ws = (char*)d_ws;
        unsigned* hist   = (unsigned*)(ws + WSO_HIST);
        unsigned* cursor = (unsigned*)(ws + WSO_CURSOR);
        unsigned* sortP  = (unsigned*)(ws + WSO_SORTP);
        float2*   wA     = (float2*)  (ws + WSO_WA);
        float2*   wB     = (float2*)  (ws + WSO_WB);
        ushort*   lutT   = (ushort*)  (ws + WSO_LUT);

        int n_chunks = D4 * NL * 4;                   // 1,336,336 4-half chunks
        dim3 grid_t((n_chunks + 255) / 256);
        hipLaunchKernelGGL(lut_transpose_h_kernel, grid_t, block, 0, stream,
                           (const float4*)lut, lutT);
        hipLaunchKernelGGL(lut4d_zero_meta, dim3(1), block, 0, stream,
                           (unsigned*)ws);
        hipLaunchKernelGGL(lut4d_hist, dim3(NPIX / 256), block, 0, stream,
                           x, hist);
        hipLaunchKernelGGL(lut4d_scan, dim3(1), block, 0, stream,
                           hist, cursor);
        hipLaunchKernelGGL(lut4d_scatter, dim3(NPIX / 256), block, 0, stream,
                           x, weight, cursor, sortP, wA, wB);
        hipLaunchKernelGGL(lut4d_main_sorted, dim3(8192), block, 0, stream,
                           lutT, sortP, wA, wB, x, out);
    } else {
        dim3 grid_main(1024);
        hipLaunchKernelGGL(lut4d_kernel_fallback, grid_main, block, 0, stream,
                           lut, weight, x, out);
    }
}